// Round 2
// baseline (1188158.984 us; speedup 1.0000x reference)
//
#include <hip/hip_runtime.h>

// ============================================================================
// Two-level LSTM (char k-mer LSTM -> word LSTM), MI355X.
//
// Persistent multi-WG recurrence kernels. All worker WGs are ELECTED onto a
// single XCD (pigeonhole over 8 XCDs with an oversubscribed grid), so the
// per-step h exchange stays in that XCD's L2: producer publishes tagged
// 8-byte slots with workgroup-scope stores (write-through L1 -> L2),
// consumers poll with sc0 loads (bypass L1, read shared L2, ~200 cyc RTT
// instead of ~900 at the IF$ coherence point). Each publish is mirrored to
// an agent-scope slot array; polls fall back to the mirror after 512 spins
// (safety net: staleness bug => slow, never a hang).
// Tag layout: (step+1)<<32 | f32bits(h), double-buffered by step parity.
// 2-slot parity is race-free: publish(t+1) requires poll(t) on all waves of
// all WGs (per-WG barrier sits between poll and publish), so no consumer
// still needs tag t-1 when it is overwritten.
// ============================================================================

#define S_LEN 4096
#define TCH   16384        // S_LEN * 4 char steps
#define ALPHA 25
#define ECH   64
#define HR    256
#define DL    128
#define EW    128
#define HW    512
#define NWC   16           // char-LSTM worker WGs (16 units each)
#define GRIDC 128          // oversubscribed grid: ceil(128/8)=16 on some XCD
#define NWW   32           // word-LSTM worker WGs (16 units each)
#define GRIDW 256          // ceil(256/8)=32 on some XCD

static __device__ __forceinline__ float fsigmoid(float x) {
  x = fminf(fmaxf(x, -30.f), 30.f);
  return __builtin_amdgcn_rcpf(1.0f + __expf(-x));
}
static __device__ __forceinline__ float ftanh(float x) {
  x = fminf(fmaxf(x, -15.f), 15.f);
  float e = __expf(2.0f * x);
  return 1.0f - 2.0f * __builtin_amdgcn_rcpf(e + 1.0f);
}

// sc0 load: bypass L1, read the XCD-shared L2 (the coherence point for
// same-XCD CUs). Mirror fallback is agent-scope (IF$-coherent).
static __device__ __forceinline__ unsigned long long poll_slot(
    const unsigned long long* sl, const unsigned long long* slm, unsigned tag) {
  unsigned long long v;
  int spins = 0;
  for (;;) {
    asm volatile("global_load_dwordx2 %0, %1, off sc0\n\t"
                 "s_waitcnt vmcnt(0)"
                 : "=v"(v) : "v"(sl) : "memory");
    if ((unsigned)(v >> 32) == tag) return v;
    if (++spins >= 512) {
      v = __hip_atomic_load(slm, __ATOMIC_RELAXED, __HIP_MEMORY_SCOPE_AGENT);
      if ((unsigned)(v >> 32) == tag) return v;
      spins = 0;
    }
  }
}

// Deadlock-free single-XCD role election. el: [0..7]=cnt, [8]=winner(-1),
// [9]=role_cnt (zeroed by k_init each launch). Every WG registers; by
// pigeonhole some XCD reaches NW registrants and becomes the winner; the
// first NW WGs on the winner claim roles 0..NW-1, everyone else exits.
static __device__ __forceinline__ int elect_role(int* el, int NW) {
  unsigned xcd;
  asm volatile("s_getreg_b32 %0, hwreg(HW_REG_XCC_ID)" : "=s"(xcd));
  xcd &= 7u;
  int r = __hip_atomic_fetch_add(&el[xcd], 1, __ATOMIC_RELAXED,
                                 __HIP_MEMORY_SCOPE_AGENT);
  if (r == NW - 1) {
    int exp = -1;
    __hip_atomic_compare_exchange_strong(&el[8], &exp, (int)xcd,
        __ATOMIC_RELAXED, __ATOMIC_RELAXED, __HIP_MEMORY_SCOPE_AGENT);
  }
  int w;
  while ((w = __hip_atomic_load(&el[8], __ATOMIC_RELAXED,
                                __HIP_MEMORY_SCOPE_AGENT)) < 0) {}
  if (w != (int)xcd) return -1;
  int rr = __hip_atomic_fetch_add(&el[9], 1, __ATOMIC_RELAXED,
                                  __HIP_MEMORY_SCOPE_AGENT);
  return (rr < NW) ? rr : -1;
}

__global__ void k_init(int* ec, int* ew) {
  int t = threadIdx.x;
  if (t < 10) ec[t] = (t == 8) ? -1 : 0;
  else if (t < 20) { int u = t - 10; ew[u] = (u == 8) ? -1 : 0; }
}

// ---------------------------------------------------------------------------
// K1a: char gate-input table: table[a][row] = b_r[row] + E_char[a,:]·W_ih_r[row,:]
// ---------------------------------------------------------------------------
__global__ void k_table(const float* __restrict__ Ec, const float* __restrict__ Wih,
                        const float* __restrict__ br, float* __restrict__ table) {
  __shared__ __align__(16) float e[ECH];
  int a = blockIdx.x, tid = threadIdx.x;
  if (tid < ECH) e[tid] = Ec[a * ECH + tid];
  __syncthreads();
  for (int row = tid; row < 4 * HR; row += 256) {
    const float4* w = (const float4*)(Wih + row * ECH);
    const float4* e4 = (const float4*)e;
    float acc = 0.f;
#pragma unroll
    for (int j = 0; j < ECH / 4; ++j) {
      float4 wv = w[j], ev = e4[j];
      acc += wv.x * ev.x + wv.y * ev.y + wv.z * ev.z + wv.w * ev.w;
    }
    table[a * (4 * HR) + row] = acc + br[row];
  }
}

// ---------------------------------------------------------------------------
// K1b: permute W_ih_w into k-major layout WT[k][p], p = (wg,gate,unit).
// ---------------------------------------------------------------------------
__global__ void k_permw(const float* __restrict__ Wihw, const float* __restrict__ bw,
                        float* __restrict__ WT, float* __restrict__ bperm) {
  int e = blockIdx.x * 256 + threadIdx.x;
  int p = e >> 8, k = e & 255;
  int r = p & 63, wgp = p >> 6;
  int R = (r >> 4) * HW + wgp * 16 + (r & 15);
  WT[k * (4 * HW) + p] = Wihw[R * (EW + DL) + k];
  if (k == 0) bperm[p] = bw[R];
}

// ---------------------------------------------------------------------------
// K2: persistent char LSTM. NWC WGs x 256 threads, all on one XCD.
// ---------------------------------------------------------------------------
__global__ __launch_bounds__(256) void k_char_lstm(
    const int* __restrict__ char_ids, const float* __restrict__ Whh,
    const float* __restrict__ table, unsigned long long* __restrict__ slots,
    unsigned long long* __restrict__ slotsM, int* __restrict__ elect,
    float* __restrict__ h_word)
{
  __shared__ int role_sh;
  if (threadIdx.x == 0) role_sh = elect_role(elect, NWC);
  __syncthreads();
  const int wg = role_sh;
  if (wg < 0) return;

  const int tid = threadIdx.x;
  const int wave = tid >> 6, lane = tid & 63;
  const int R = (lane >> 4) * HR + wg * 16 + (lane & 15);
  float4 wreg[16];
  {
    const float4* wp = (const float4*)(Whh + R * HR + wave * 64);
#pragma unroll
    for (int j = 0; j < 16; ++j) wreg[j] = wp[j];
  }
  __shared__ __align__(16) float tab[ALPHA * 64];
  __shared__ __align__(16) float hst[4][64];
  __shared__ float part[2][4][64];
  __shared__ float cst[16];
  for (int i = tid; i < ALPHA * 64; i += 256) {
    int chh = i >> 6, r = i & 63;
    int Rr = (r >> 4) * HR + wg * 16 + (r & 15);
    tab[i] = table[chh * (4 * HR) + Rr];
  }
  hst[wave][lane] = 0.f;
  if (tid < 16) cst[tid] = 0.f;
  __syncthreads();

#pragma unroll 1
  for (int t = 0; t < TCH; ++t) {
    int ch = char_ids[t];                    // uniform; overlaps the poll
    if (t > 0) {
      int par = (t - 1) & 1;
      unsigned long long v = poll_slot(slots + par * HR + tid,
                                       slotsM + par * HR + tid, (unsigned)t);
      hst[wave][lane] = __uint_as_float((unsigned)v);
      // same-wave LDS write->read; no barrier needed.
    }
    const float4* hp = (const float4*)hst[wave];
    float a0 = 0.f, a1 = 0.f, a2 = 0.f, a3 = 0.f;   // 4 chains: break FMA dep
#pragma unroll
    for (int j = 0; j < 4; ++j) {
      float4 h0 = hp[4*j+0], h1 = hp[4*j+1], h2 = hp[4*j+2], h3 = hp[4*j+3];
      float4 w0 = wreg[4*j+0], w1 = wreg[4*j+1], w2 = wreg[4*j+2], w3 = wreg[4*j+3];
      a0 += w0.x*h0.x + w0.y*h0.y + w0.z*h0.z + w0.w*h0.w;
      a1 += w1.x*h1.x + w1.y*h1.y + w1.z*h1.z + w1.w*h1.w;
      a2 += w2.x*h2.x + w2.y*h2.y + w2.z*h2.z + w2.w*h2.w;
      a3 += w3.x*h3.x + w3.y*h3.y + w3.z*h3.z + w3.w*h3.w;
    }
    float acc = (a0 + a1) + (a2 + a3);
    const int par = t & 1;
    part[par][wave][lane] = acc;
    __syncthreads();                          // single barrier per step
    if (wave == 0) {
      float z = ((part[par][0][lane] + part[par][1][lane]) +
                 (part[par][2][lane] + part[par][3][lane])) + tab[ch * 64 + lane];
      int u = lane & 15;                      // gate gather via shuffles
      float zi = __shfl(z, u,      64);
      float zf = __shfl(z, u + 16, 64);
      float zg = __shfl(z, u + 32, 64);
      float zo = __shfl(z, u + 48, 64);
      if (lane < 16) {
        float c = cst[lane];
        float ig = fsigmoid(zi), fg = fsigmoid(zf), og = fsigmoid(zo);
        float gg = ftanh(zg);
        c = fg * c + ig * gg;
        cst[lane] = c;
        float h = og * ftanh(c);
        unsigned long long pv =
            (((unsigned long long)(unsigned)(t + 1)) << 32) |
            (unsigned long long)__float_as_uint(h);
        int si = par * HR + wg * 16 + lane;
        __hip_atomic_store(slots + si, pv, __ATOMIC_RELAXED,
                           __HIP_MEMORY_SCOPE_WORKGROUP);  // L2-local publish
        __hip_atomic_store(slotsM + si, pv, __ATOMIC_RELAXED,
                           __HIP_MEMORY_SCOPE_AGENT);      // mirror (fallback)
        if ((t & 3) == 3) h_word[(t >> 2) * HR + wg * 16 + lane] = h;
      }
    }
    // no trailing barrier: part[] is parity-buffered; wave0 finishes reading
    // part[par] before it reaches the NEXT barrier, which gates overwrites.
  }
}

// ---------------------------------------------------------------------------
// K3a: latent = tanh(h_word @ W_lat^T + b_lat). One block per word.
// ---------------------------------------------------------------------------
__global__ __launch_bounds__(128) void k_latent(
    const float* __restrict__ hw, const float* __restrict__ Wlat,
    const float* __restrict__ blat, float* __restrict__ lat)
{
  int t = blockIdx.x, d = threadIdx.x;
  __shared__ __align__(16) float hh[HR];
  ((float2*)hh)[d] = ((const float2*)(hw + t * HR))[d];
  __syncthreads();
  const float4* w = (const float4*)(Wlat + d * HR);
  const float4* h4 = (const float4*)hh;
  float acc = 0.f;
#pragma unroll 8
  for (int j = 0; j < HR / 4; ++j) {
    float4 wv = w[j], hv = h4[j];
    acc += wv.x * hv.x + wv.y * hv.y + wv.z * hv.z + wv.w * hv.w;
  }
  lat[t * DL + d] = tanhf(acc + blat[d]);
}

// ---------------------------------------------------------------------------
// K3b: Xw[t][p] = bperm[p] + concat(E_word[wid[t]], latent[t]) · W row(p)
// ---------------------------------------------------------------------------
__global__ __launch_bounds__(256) void k_xw(
    const float* __restrict__ Ew, const int* __restrict__ wid,
    const float* __restrict__ lat, const float* __restrict__ WT,
    const float* __restrict__ bperm, float* __restrict__ Xw)
{
  int tblk = blockIdx.x, pblk = blockIdx.y;
  int tid = threadIdx.x;
  int p = pblk * 256 + tid;
  __shared__ __align__(16) float xt[32][256];
  int t0 = tblk * 32;
  for (int i = tid; i < 32 * 256; i += 256) {
    int tl = i >> 8, e = i & 255;
    int t = t0 + tl;
    float v;
    if (e < 128) v = Ew[wid[t] * EW + e];
    else         v = lat[t * DL + (e - 128)];
    xt[tl][e] = v;
  }
  __syncthreads();
  float acc[32];
#pragma unroll
  for (int i = 0; i < 32; ++i) acc[i] = 0.f;
  for (int k = 0; k < 256; k += 4) {
    float w0 = WT[(k + 0) * (4 * HW) + p];
    float w1 = WT[(k + 1) * (4 * HW) + p];
    float w2 = WT[(k + 2) * (4 * HW) + p];
    float w3 = WT[(k + 3) * (4 * HW) + p];
#pragma unroll
    for (int tl = 0; tl < 32; ++tl) {
      float4 x4 = *(const float4*)&xt[tl][k];
      acc[tl] += w0 * x4.x + w1 * x4.y + w2 * x4.z + w3 * x4.w;
    }
  }
  float b = bperm[p];
#pragma unroll
  for (int tl = 0; tl < 32; ++tl)
    Xw[(t0 + tl) * (4 * HW) + p] = acc[tl] + b;
}

// ---------------------------------------------------------------------------
// K4: persistent word LSTM. NWW WGs x 512 threads (8 waves), one XCD.
// ---------------------------------------------------------------------------
__global__ __launch_bounds__(512) void k_word_lstm(
    const float* __restrict__ Whh, const float* __restrict__ Xw,
    unsigned long long* __restrict__ slots, unsigned long long* __restrict__ slotsM,
    int* __restrict__ elect, float* __restrict__ out)
{
  __shared__ int role_sh;
  if (threadIdx.x == 0) role_sh = elect_role(elect, NWW);
  __syncthreads();
  const int wg = role_sh;
  if (wg < 0) return;

  const int tid = threadIdx.x;
  const int wave = tid >> 6, lane = tid & 63;
  const int R = (lane >> 4) * HW + wg * 16 + (lane & 15);
  float4 wreg[16];
  {
    const float4* wp = (const float4*)(Whh + R * HW + wave * 64);
#pragma unroll
    for (int j = 0; j < 16; ++j) wreg[j] = wp[j];
  }
  __shared__ __align__(16) float hst[8][64];
  __shared__ float part[2][8][64];
  __shared__ float cst[16];
  hst[wave][lane] = 0.f;
  if (tid < 16) cst[tid] = 0.f;
  __syncthreads();
  float xv = 0.f;
  if (wave == 0) xv = Xw[wg * 64 + lane];    // t=0 slice

#pragma unroll 1
  for (int t = 0; t < S_LEN; ++t) {
    float xn = 0.f;
    if (wave == 0) {                         // prefetch next x-slice
      int tt = (t + 1 < S_LEN) ? (t + 1) : t;
      xn = Xw[tt * (4 * HW) + wg * 64 + lane];
    }
    if (t > 0) {
      int par = (t - 1) & 1;
      unsigned long long v = poll_slot(slots + par * HW + tid,
                                       slotsM + par * HW + tid, (unsigned)t);
      hst[wave][lane] = __uint_as_float((unsigned)v);
    }
    const float4* hp = (const float4*)hst[wave];
    float a0 = 0.f, a1 = 0.f, a2 = 0.f, a3 = 0.f;
#pragma unroll
    for (int j = 0; j < 4; ++j) {
      float4 h0 = hp[4*j+0], h1 = hp[4*j+1], h2 = hp[4*j+2], h3 = hp[4*j+3];
      float4 w0 = wreg[4*j+0], w1 = wreg[4*j+1], w2 = wreg[4*j+2], w3 = wreg[4*j+3];
      a0 += w0.x*h0.x + w0.y*h0.y + w0.z*h0.z + w0.w*h0.w;
      a1 += w1.x*h1.x + w1.y*h1.y + w1.z*h1.z + w1.w*h1.w;
      a2 += w2.x*h2.x + w2.y*h2.y + w2.z*h2.z + w2.w*h2.w;
      a3 += w3.x*h3.x + w3.y*h3.y + w3.z*h3.z + w3.w*h3.w;
    }
    float acc = (a0 + a1) + (a2 + a3);
    const int par = t & 1;
    part[par][wave][lane] = acc;
    __syncthreads();
    if (wave == 0) {
      float z = (((part[par][0][lane] + part[par][1][lane]) +
                  (part[par][2][lane] + part[par][3][lane])) +
                 ((part[par][4][lane] + part[par][5][lane]) +
                  (part[par][6][lane] + part[par][7][lane]))) + xv;
      int u = lane & 15;
      float zi = __shfl(z, u,      64);
      float zf = __shfl(z, u + 16, 64);
      float zg = __shfl(z, u + 32, 64);
      float zo = __shfl(z, u + 48, 64);
      if (lane < 16) {
        float c = cst[lane];
        float ig = fsigmoid(zi), fg = fsigmoid(zf), og = fsigmoid(zo);
        float gg = ftanh(zg);
        c = fg * c + ig * gg;
        cst[lane] = c;
        float h = og * ftanh(c);
        unsigned long long pv =
            (((unsigned long long)(unsigned)(t + 1)) << 32) |
            (unsigned long long)__float_as_uint(h);
        int si = par * HW + wg * 16 + lane;
        __hip_atomic_store(slots + si, pv, __ATOMIC_RELAXED,
                           __HIP_MEMORY_SCOPE_WORKGROUP);
        __hip_atomic_store(slotsM + si, pv, __ATOMIC_RELAXED,
                           __HIP_MEMORY_SCOPE_AGENT);
        out[t * HW + wg * 16 + lane] = h;
      }
    }
    xv = xn;
  }
}

// ---------------------------------------------------------------------------
extern "C" void kernel_launch(void* const* d_in, const int* in_sizes, int n_in,
                              void* d_out, int out_size, void* d_ws, size_t ws_size,
                              hipStream_t stream) {
  const float* E_char = (const float*)d_in[0];
  const float* W_ih_r = (const float*)d_in[1];
  const float* W_hh_r = (const float*)d_in[2];
  const float* b_r    = (const float*)d_in[3];
  const float* W_lat  = (const float*)d_in[4];
  const float* b_lat  = (const float*)d_in[5];
  const float* E_word = (const float*)d_in[6];
  const float* W_ih_w = (const float*)d_in[7];
  const float* W_hh_w = (const float*)d_in[8];
  const float* b_w    = (const float*)d_in[9];
  const int* word_ids = (const int*)d_in[10];
  const int* char_ids = (const int*)d_in[11];

  char* ws = (char*)d_ws;
  float*              tableR  = (float*)(ws + 0x000000);             // 100 KB
  unsigned long long* slotsC  = (unsigned long long*)(ws + 0x20000); // 4 KB
  unsigned long long* slotsCM = (unsigned long long*)(ws + 0x22000); // 4 KB
  unsigned long long* slotsW  = (unsigned long long*)(ws + 0x24000); // 8 KB
  unsigned long long* slotsWM = (unsigned long long*)(ws + 0x26000); // 8 KB
  int*                electC  = (int*)(ws + 0x28000);
  int*                electW  = (int*)(ws + 0x28100);
  float*              h_word  = (float*)(ws + 0x030000);             // 4 MB
  float*              latent  = (float*)(ws + 0x430000);             // 2 MB
  float*              WT      = (float*)(ws + 0x630000);             // 2 MB
  float*              bperm   = (float*)(ws + 0x830000);             // 8 KB
  float*              Xw      = (float*)(ws + 0x840000);             // 32 MB
  float* out = (float*)d_out;

  hipLaunchKernelGGL(k_init,      dim3(1),       dim3(64),  0, stream,
                     electC, electW);
  hipLaunchKernelGGL(k_table,     dim3(ALPHA),   dim3(256), 0, stream,
                     E_char, W_ih_r, b_r, tableR);
  hipLaunchKernelGGL(k_permw,     dim3(2048),    dim3(256), 0, stream,
                     W_ih_w, b_w, WT, bperm);
  hipLaunchKernelGGL(k_char_lstm, dim3(GRIDC),   dim3(256), 0, stream,
                     char_ids, W_hh_r, tableR, slotsC, slotsCM, electC, h_word);
  hipLaunchKernelGGL(k_latent,    dim3(S_LEN),   dim3(128), 0, stream,
                     h_word, W_lat, b_lat, latent);
  hipLaunchKernelGGL(k_xw,        dim3(128, 8),  dim3(256), 0, stream,
                     E_word, word_ids, latent, WT, bperm, Xw);
  hipLaunchKernelGGL(k_word_lstm, dim3(GRIDW),   dim3(512), 0, stream,
                     W_hh_w, Xw, slotsW, slotsWM, electW, out);
}

// Round 3
// 33528.308 us; speedup vs baseline: 35.4375x; 35.4375x over previous
//
#include <hip/hip_runtime.h>

// ============================================================================
// Two-level LSTM (char k-mer LSTM -> word LSTM), MI355X.
//
// Persistent multi-WG recurrence kernels, all worker WGs elected onto ONE XCD
// (pigeonhole election over an oversubscribed grid, HW_REG_XCC_ID).
// Per-step h exchange via tagged 8-byte slots, (tag)<<32 | f32bits(h),
// double-buffered by step parity:
//   - FAST path: producer publishes with `global_store_dwordx2 ... sc0`
//     (SE scope: forced write-through L1 -> XCD-shared L2); consumers poll
//     with `global_load_dwordx2 ... sc0` (bypass L1, read shared L2).
//     R2 lesson: a plain (no-flag) store can linger in L1 (write-back on
//     CDNA4) and NEVER reach L2 -- the sc0 store is the fix.
//   - MIRROR fallback: agent-scope atomics (R1's known-working path),
//     interleaved 1 mirror probe per 2 fast probes -- worst case ~1.2x R1,
//     never a timeout stall, never a hang.
// Per-step barrier is `s_waitcnt lgkmcnt(0); s_barrier` (no vmcnt drain, so
// mirror stores keep draining in the background). part[] is parity-buffered;
// the single-barrier protocol is race-free: publish(t+3) by WG A requires
// A polled t+2, which requires every WG published t+2, which requires every
// wave of every WG consumed t+1 -- so overwriting tag t+1 is safe.
// ============================================================================

#define S_LEN 4096
#define TCH   16384        // S_LEN * 4 char steps
#define ALPHA 25
#define ECH   64
#define HR    256
#define DL    128
#define EW    128
#define HW    512
#define NWC   16           // char-LSTM worker WGs (16 units each)
#define GRIDC 128          // ceil(128/8)=16 on some XCD
#define NWW   32           // word-LSTM worker WGs (16 units each)
#define GRIDW 256          // ceil(256/8)=32 on some XCD

static __device__ __forceinline__ float fsigmoid(float x) {
  x = fminf(fmaxf(x, -30.f), 30.f);
  return __builtin_amdgcn_rcpf(1.0f + __expf(-x));
}
static __device__ __forceinline__ float ftanh(float x) {
  x = fminf(fmaxf(x, -15.f), 15.f);
  float e = __expf(2.0f * x);
  return 1.0f - 2.0f * __builtin_amdgcn_rcpf(e + 1.0f);
}

// LDS-only barrier: orders LDS traffic across waves without draining the
// vmem queue (keeps agent mirror stores fire-and-forget).
static __device__ __forceinline__ void barrier_lds() {
  asm volatile("s_waitcnt lgkmcnt(0)\n\ts_barrier" ::: "memory");
}

// Poll: 2 fast (L2, sc0) probes, then 1 agent mirror probe, repeat.
static __device__ __forceinline__ unsigned long long poll_slot(
    const unsigned long long* fast, const unsigned long long* mir, unsigned tag) {
  unsigned long long v;
  for (;;) {
#pragma unroll
    for (int k = 0; k < 2; ++k) {
      asm volatile("global_load_dwordx2 %0, %1, off sc0\n\t"
                   "s_waitcnt vmcnt(0)"
                   : "=v"(v) : "v"(fast) : "memory");
      if ((unsigned)(v >> 32) == tag) return v;
    }
    v = __hip_atomic_load(mir, __ATOMIC_RELAXED, __HIP_MEMORY_SCOPE_AGENT);
    if ((unsigned)(v >> 32) == tag) return v;
  }
}

// Publish: sc0 store (write-through to shared L2) + agent mirror.
static __device__ __forceinline__ void publish_slot(
    unsigned long long* fast, unsigned long long* mir, unsigned long long pv) {
  asm volatile("global_store_dwordx2 %0, %1, off sc0"
               :: "v"(fast), "v"(pv) : "memory");
  __hip_atomic_store(mir, pv, __ATOMIC_RELAXED, __HIP_MEMORY_SCOPE_AGENT);
}

// Deadlock-free single-XCD role election (el: [0..7]=cnt, [8]=winner(-1),
// [9]=role_cnt; zeroed by k_init each launch). Pigeonhole guarantees some
// XCD reaches NW registrants; first to do so wins; others exit.
static __device__ __forceinline__ int elect_role(int* el, int NW) {
  unsigned xcd;
  asm volatile("s_getreg_b32 %0, hwreg(HW_REG_XCC_ID)" : "=s"(xcd));
  xcd &= 7u;
  int r = __hip_atomic_fetch_add(&el[xcd], 1, __ATOMIC_RELAXED,
                                 __HIP_MEMORY_SCOPE_AGENT);
  if (r == NW - 1) {
    int exp = -1;
    __hip_atomic_compare_exchange_strong(&el[8], &exp, (int)xcd,
        __ATOMIC_RELAXED, __ATOMIC_RELAXED, __HIP_MEMORY_SCOPE_AGENT);
  }
  int w;
  while ((w = __hip_atomic_load(&el[8], __ATOMIC_RELAXED,
                                __HIP_MEMORY_SCOPE_AGENT)) < 0) {}
  if (w != (int)xcd) return -1;
  int rr = __hip_atomic_fetch_add(&el[9], 1, __ATOMIC_RELAXED,
                                  __HIP_MEMORY_SCOPE_AGENT);
  return (rr < NW) ? rr : -1;
}

__global__ void k_init(int* ec, int* ew) {
  int t = threadIdx.x;
  if (t < 10) ec[t] = (t == 8) ? -1 : 0;
  else if (t < 20) { int u = t - 10; ew[u] = (u == 8) ? -1 : 0; }
}

// ---------------------------------------------------------------------------
// K1a: char gate-input table: table[a][row] = b_r[row] + E_char[a,:]·W_ih_r[row,:]
// ---------------------------------------------------------------------------
__global__ void k_table(const float* __restrict__ Ec, const float* __restrict__ Wih,
                        const float* __restrict__ br, float* __restrict__ table) {
  __shared__ __align__(16) float e[ECH];
  int a = blockIdx.x, tid = threadIdx.x;
  if (tid < ECH) e[tid] = Ec[a * ECH + tid];
  __syncthreads();
  for (int row = tid; row < 4 * HR; row += 256) {
    const float4* w = (const float4*)(Wih + row * ECH);
    const float4* e4 = (const float4*)e;
    float acc = 0.f;
#pragma unroll
    for (int j = 0; j < ECH / 4; ++j) {
      float4 wv = w[j], ev = e4[j];
      acc += wv.x * ev.x + wv.y * ev.y + wv.z * ev.z + wv.w * ev.w;
    }
    table[a * (4 * HR) + row] = acc + br[row];
  }
}

// ---------------------------------------------------------------------------
// K1b: permute W_ih_w into k-major layout WT[k][p], p = (wg,gate,unit).
// ---------------------------------------------------------------------------
__global__ void k_permw(const float* __restrict__ Wihw, const float* __restrict__ bw,
                        float* __restrict__ WT, float* __restrict__ bperm) {
  int e = blockIdx.x * 256 + threadIdx.x;
  int p = e >> 8, k = e & 255;
  int r = p & 63, wgp = p >> 6;
  int R = (r >> 4) * HW + wgp * 16 + (r & 15);
  WT[k * (4 * HW) + p] = Wihw[R * (EW + DL) + k];
  if (k == 0) bperm[p] = bw[R];
}

// ---------------------------------------------------------------------------
// K2: persistent char LSTM. NWC WGs x 256 threads, elected onto one XCD.
// ---------------------------------------------------------------------------
__global__ __launch_bounds__(256) void k_char_lstm(
    const int* __restrict__ char_ids, const float* __restrict__ Whh,
    const float* __restrict__ table, unsigned long long* __restrict__ slots,
    unsigned long long* __restrict__ slotsM, int* __restrict__ elect,
    float* __restrict__ h_word)
{
  __shared__ int role_sh;
  if (threadIdx.x == 0) role_sh = elect_role(elect, NWC);
  __syncthreads();
  const int wg = role_sh;
  if (wg < 0) return;

  const int tid = threadIdx.x;
  const int wave = tid >> 6, lane = tid & 63;
  const int R = (lane >> 4) * HR + wg * 16 + (lane & 15);
  float4 wreg[16];
  {
    const float4* wp = (const float4*)(Whh + R * HR + wave * 64);
#pragma unroll
    for (int j = 0; j < 16; ++j) wreg[j] = wp[j];
  }
  __shared__ __align__(16) float tab[ALPHA * 64];
  __shared__ __align__(16) float hst[4][64];
  __shared__ float part[2][4][64];
  __shared__ float cst[16];
  for (int i = tid; i < ALPHA * 64; i += 256) {
    int chh = i >> 6, r = i & 63;
    int Rr = (r >> 4) * HR + wg * 16 + (r & 15);
    tab[i] = table[chh * (4 * HR) + Rr];
  }
  hst[wave][lane] = 0.f;
  if (tid < 16) cst[tid] = 0.f;
  __syncthreads();

#pragma unroll 1
  for (int t = 0; t < TCH; ++t) {
    int ch = char_ids[t];                    // uniform; overlaps the poll
    if (t > 0) {
      int par = (t - 1) & 1;
      unsigned long long v = poll_slot(slots + par * HR + tid,
                                       slotsM + par * HR + tid, (unsigned)t);
      hst[wave][lane] = __uint_as_float((unsigned)v);
      // same-wave LDS write->read; no barrier needed.
    }
    const float4* hp = (const float4*)hst[wave];
    float a0 = 0.f, a1 = 0.f, a2 = 0.f, a3 = 0.f;   // 4 chains: break FMA dep
#pragma unroll
    for (int j = 0; j < 4; ++j) {
      float4 h0 = hp[4*j+0], h1 = hp[4*j+1], h2 = hp[4*j+2], h3 = hp[4*j+3];
      float4 w0 = wreg[4*j+0], w1 = wreg[4*j+1], w2 = wreg[4*j+2], w3 = wreg[4*j+3];
      a0 += w0.x*h0.x + w0.y*h0.y + w0.z*h0.z + w0.w*h0.w;
      a1 += w1.x*h1.x + w1.y*h1.y + w1.z*h1.z + w1.w*h1.w;
      a2 += w2.x*h2.x + w2.y*h2.y + w2.z*h2.z + w2.w*h2.w;
      a3 += w3.x*h3.x + w3.y*h3.y + w3.z*h3.z + w3.w*h3.w;
    }
    float acc = (a0 + a1) + (a2 + a3);
    const int par = t & 1;
    part[par][wave][lane] = acc;
    barrier_lds();                            // LDS-only barrier per step
    if (wave == 0) {
      float z = ((part[par][0][lane] + part[par][1][lane]) +
                 (part[par][2][lane] + part[par][3][lane])) + tab[ch * 64 + lane];
      int u = lane & 15;                      // gate gather via shuffles
      float zi = __shfl(z, u,      64);
      float zf = __shfl(z, u + 16, 64);
      float zg = __shfl(z, u + 32, 64);
      float zo = __shfl(z, u + 48, 64);
      if (lane < 16) {
        float c = cst[lane];
        float ig = fsigmoid(zi), fg = fsigmoid(zf), og = fsigmoid(zo);
        float gg = ftanh(zg);
        c = fg * c + ig * gg;
        cst[lane] = c;
        float h = og * ftanh(c);
        unsigned long long pv =
            (((unsigned long long)(unsigned)(t + 1)) << 32) |
            (unsigned long long)__float_as_uint(h);
        int si = par * HR + wg * 16 + lane;
        publish_slot(slots + si, slotsM + si, pv);
        if ((t & 3) == 3) h_word[(t >> 2) * HR + wg * 16 + lane] = h;
      }
    }
    // no trailing barrier: part[] is parity-buffered (race-freedom in header).
  }
}

// ---------------------------------------------------------------------------
// K3a: latent = tanh(h_word @ W_lat^T + b_lat). One block per word.
// ---------------------------------------------------------------------------
__global__ __launch_bounds__(128) void k_latent(
    const float* __restrict__ hw, const float* __restrict__ Wlat,
    const float* __restrict__ blat, float* __restrict__ lat)
{
  int t = blockIdx.x, d = threadIdx.x;
  __shared__ __align__(16) float hh[HR];
  ((float2*)hh)[d] = ((const float2*)(hw + t * HR))[d];
  __syncthreads();
  const float4* w = (const float4*)(Wlat + d * HR);
  const float4* h4 = (const float4*)hh;
  float acc = 0.f;
#pragma unroll 8
  for (int j = 0; j < HR / 4; ++j) {
    float4 wv = w[j], hv = h4[j];
    acc += wv.x * hv.x + wv.y * hv.y + wv.z * hv.z + wv.w * hv.w;
  }
  lat[t * DL + d] = tanhf(acc + blat[d]);
}

// ---------------------------------------------------------------------------
// K3b: Xw[t][p] = bperm[p] + concat(E_word[wid[t]], latent[t]) · W row(p)
// ---------------------------------------------------------------------------
__global__ __launch_bounds__(256) void k_xw(
    const float* __restrict__ Ew, const int* __restrict__ wid,
    const float* __restrict__ lat, const float* __restrict__ WT,
    const float* __restrict__ bperm, float* __restrict__ Xw)
{
  int tblk = blockIdx.x, pblk = blockIdx.y;
  int tid = threadIdx.x;
  int p = pblk * 256 + tid;
  __shared__ __align__(16) float xt[32][256];
  int t0 = tblk * 32;
  for (int i = tid; i < 32 * 256; i += 256) {
    int tl = i >> 8, e = i & 255;
    int t = t0 + tl;
    float v;
    if (e < 128) v = Ew[wid[t] * EW + e];
    else         v = lat[t * DL + (e - 128)];
    xt[tl][e] = v;
  }
  __syncthreads();
  float acc[32];
#pragma unroll
  for (int i = 0; i < 32; ++i) acc[i] = 0.f;
  for (int k = 0; k < 256; k += 4) {
    float w0 = WT[(k + 0) * (4 * HW) + p];
    float w1 = WT[(k + 1) * (4 * HW) + p];
    float w2 = WT[(k + 2) * (4 * HW) + p];
    float w3 = WT[(k + 3) * (4 * HW) + p];
#pragma unroll
    for (int tl = 0; tl < 32; ++tl) {
      float4 x4 = *(const float4*)&xt[tl][k];
      acc[tl] += w0 * x4.x + w1 * x4.y + w2 * x4.z + w3 * x4.w;
    }
  }
  float b = bperm[p];
#pragma unroll
  for (int tl = 0; tl < 32; ++tl)
    Xw[(t0 + tl) * (4 * HW) + p] = acc[tl] + b;
}

// ---------------------------------------------------------------------------
// K4: persistent word LSTM. NWW WGs x 512 threads (8 waves), one XCD.
// ---------------------------------------------------------------------------
__global__ __launch_bounds__(512) void k_word_lstm(
    const float* __restrict__ Whh, const float* __restrict__ Xw,
    unsigned long long* __restrict__ slots, unsigned long long* __restrict__ slotsM,
    int* __restrict__ elect, float* __restrict__ out)
{
  __shared__ int role_sh;
  if (threadIdx.x == 0) role_sh = elect_role(elect, NWW);
  __syncthreads();
  const int wg = role_sh;
  if (wg < 0) return;

  const int tid = threadIdx.x;
  const int wave = tid >> 6, lane = tid & 63;
  const int R = (lane >> 4) * HW + wg * 16 + (lane & 15);
  float4 wreg[16];
  {
    const float4* wp = (const float4*)(Whh + R * HW + wave * 64);
#pragma unroll
    for (int j = 0; j < 16; ++j) wreg[j] = wp[j];
  }
  __shared__ __align__(16) float hst[8][64];
  __shared__ float part[2][8][64];
  __shared__ float cst[16];
  hst[wave][lane] = 0.f;
  if (tid < 16) cst[tid] = 0.f;
  __syncthreads();
  float xv = 0.f;
  if (wave == 0) xv = Xw[wg * 64 + lane];    // t=0 slice

#pragma unroll 1
  for (int t = 0; t < S_LEN; ++t) {
    float xn = 0.f;
    if (wave == 0) {                         // prefetch next x-slice
      int tt = (t + 1 < S_LEN) ? (t + 1) : t;
      xn = Xw[tt * (4 * HW) + wg * 64 + lane];
    }
    if (t > 0) {
      int par = (t - 1) & 1;
      unsigned long long v = poll_slot(slots + par * HW + tid,
                                       slotsM + par * HW + tid, (unsigned)t);
      hst[wave][lane] = __uint_as_float((unsigned)v);
    }
    const float4* hp = (const float4*)hst[wave];
    float a0 = 0.f, a1 = 0.f, a2 = 0.f, a3 = 0.f;
#pragma unroll
    for (int j = 0; j < 4; ++j) {
      float4 h0 = hp[4*j+0], h1 = hp[4*j+1], h2 = hp[4*j+2], h3 = hp[4*j+3];
      float4 w0 = wreg[4*j+0], w1 = wreg[4*j+1], w2 = wreg[4*j+2], w3 = wreg[4*j+3];
      a0 += w0.x*h0.x + w0.y*h0.y + w0.z*h0.z + w0.w*h0.w;
      a1 += w1.x*h1.x + w1.y*h1.y + w1.z*h1.z + w1.w*h1.w;
      a2 += w2.x*h2.x + w2.y*h2.y + w2.z*h2.z + w2.w*h2.w;
      a3 += w3.x*h3.x + w3.y*h3.y + w3.z*h3.z + w3.w*h3.w;
    }
    float acc = (a0 + a1) + (a2 + a3);
    const int par = t & 1;
    part[par][wave][lane] = acc;
    barrier_lds();
    if (wave == 0) {
      float z = (((part[par][0][lane] + part[par][1][lane]) +
                  (part[par][2][lane] + part[par][3][lane])) +
                 ((part[par][4][lane] + part[par][5][lane]) +
                  (part[par][6][lane] + part[par][7][lane]))) + xv;
      int u = lane & 15;
      float zi = __shfl(z, u,      64);
      float zf = __shfl(z, u + 16, 64);
      float zg = __shfl(z, u + 32, 64);
      float zo = __shfl(z, u + 48, 64);
      if (lane < 16) {
        float c = cst[lane];
        float ig = fsigmoid(zi), fg = fsigmoid(zf), og = fsigmoid(zo);
        float gg = ftanh(zg);
        c = fg * c + ig * gg;
        cst[lane] = c;
        float h = og * ftanh(c);
        unsigned long long pv =
            (((unsigned long long)(unsigned)(t + 1)) << 32) |
            (unsigned long long)__float_as_uint(h);
        int si = par * HW + wg * 16 + lane;
        publish_slot(slots + si, slotsM + si, pv);
        out[t * HW + wg * 16 + lane] = h;
      }
    }
    xv = xn;
  }
}

// ---------------------------------------------------------------------------
extern "C" void kernel_launch(void* const* d_in, const int* in_sizes, int n_in,
                              void* d_out, int out_size, void* d_ws, size_t ws_size,
                              hipStream_t stream) {
  const float* E_char = (const float*)d_in[0];
  const float* W_ih_r = (const float*)d_in[1];
  const float* W_hh_r = (const float*)d_in[2];
  const float* b_r    = (const float*)d_in[3];
  const float* W_lat  = (const float*)d_in[4];
  const float* b_lat  = (const float*)d_in[5];
  const float* E_word = (const float*)d_in[6];
  const float* W_ih_w = (const float*)d_in[7];
  const float* W_hh_w = (const float*)d_in[8];
  const float* b_w    = (const float*)d_in[9];
  const int* word_ids = (const int*)d_in[10];
  const int* char_ids = (const int*)d_in[11];

  char* ws = (char*)d_ws;
  float*              tableR  = (float*)(ws + 0x000000);             // 100 KB
  unsigned long long* slotsC  = (unsigned long long*)(ws + 0x20000); // 4 KB
  unsigned long long* slotsCM = (unsigned long long*)(ws + 0x22000); // 4 KB
  unsigned long long* slotsW  = (unsigned long long*)(ws + 0x24000); // 8 KB
  unsigned long long* slotsWM = (unsigned long long*)(ws + 0x26000); // 8 KB
  int*                electC  = (int*)(ws + 0x28000);
  int*                electW  = (int*)(ws + 0x28100);
  float*              h_word  = (float*)(ws + 0x030000);             // 4 MB
  float*              latent  = (float*)(ws + 0x430000);             // 2 MB
  float*              WT      = (float*)(ws + 0x630000);             // 2 MB
  float*              bperm   = (float*)(ws + 0x830000);             // 8 KB
  float*              Xw      = (float*)(ws + 0x840000);             // 32 MB
  float* out = (float*)d_out;

  hipLaunchKernelGGL(k_init,      dim3(1),       dim3(64),  0, stream,
                     electC, electW);
  hipLaunchKernelGGL(k_table,     dim3(ALPHA),   dim3(256), 0, stream,
                     E_char, W_ih_r, b_r, tableR);
  hipLaunchKernelGGL(k_permw,     dim3(2048),    dim3(256), 0, stream,
                     W_ih_w, b_w, WT, bperm);
  hipLaunchKernelGGL(k_char_lstm, dim3(GRIDC),   dim3(256), 0, stream,
                     char_ids, W_hh_r, tableR, slotsC, slotsCM, electC, h_word);
  hipLaunchKernelGGL(k_latent,    dim3(S_LEN),   dim3(128), 0, stream,
                     h_word, W_lat, b_lat, latent);
  hipLaunchKernelGGL(k_xw,        dim3(128, 8),  dim3(256), 0, stream,
                     E_word, word_ids, latent, WT, bperm, Xw);
  hipLaunchKernelGGL(k_word_lstm, dim3(GRIDW),   dim3(512), 0, stream,
                     W_hh_w, Xw, slotsW, slotsWM, electW, out);
}

// Round 4
// 28707.947 us; speedup vs baseline: 41.3878x; 1.1679x over previous
//
#include <hip/hip_runtime.h>

// ============================================================================
// Two-level LSTM (char k-mer LSTM -> word LSTM), MI355X.
//
// Persistent multi-WG recurrence kernels, all worker WGs elected onto ONE XCD
// (pigeonhole election over an oversubscribed grid, HW_REG_XCC_ID).
// Per-step h exchange via tagged 8-byte slots, (tag)<<32 | f32bits(h),
// double-buffered by step parity.
//
// R2/R3 lesson: plain or sc0 LOADS cannot reliably observe another CU's
// stores (consumer L1 serves stale lines). Fix: use ATOMICS both sides --
// atomic RMWs execute at the TCC (L2), never in the requester's L1:
//   - FAST publish: global_atomic_swap_x2 (no sc1 -> local XCD L2).
//   - FAST poll:    global_atomic_or_x2 with 0, sc0 (RMW-with-return at the
//                   local L2 -- architecturally cannot read stale L1).
//   - MIRROR fallback: agent-scope atomics (R1's known-working path),
//     interleaved 1 mirror probe per 2 fast probes -- worst case ~R3 perf,
//     never a hang.
// Per-step barrier is `s_waitcnt lgkmcnt(0); s_barrier` (no vmcnt drain).
// part[] is parity-buffered; single-barrier protocol is race-free: WG B
// can only publish tag t+1 after successfully polling tag t on ALL slots,
// and slot s holding tag t implies its owner WG fully completed poll(t-1);
// hence overwriting tag t-1 (same parity) is safe. Same-address publishes
// from the same lane are FIFO at the TCC (same channel), so tags at one
// address never reorder.
// ============================================================================

#define S_LEN 4096
#define TCH   16384        // S_LEN * 4 char steps
#define ALPHA 25
#define ECH   64
#define HR    256
#define DL    128
#define EW    128
#define HW    512
#define NWC   16           // char-LSTM worker WGs (16 units each)
#define GRIDC 128          // ceil(128/8)=16 on some XCD
#define NWW   32           // word-LSTM worker WGs (16 units each)
#define GRIDW 256          // ceil(256/8)=32 on some XCD

static __device__ __forceinline__ float fsigmoid(float x) {
  x = fminf(fmaxf(x, -30.f), 30.f);
  return __builtin_amdgcn_rcpf(1.0f + __expf(-x));
}
static __device__ __forceinline__ float ftanh(float x) {
  x = fminf(fmaxf(x, -15.f), 15.f);
  float e = __expf(2.0f * x);
  return 1.0f - 2.0f * __builtin_amdgcn_rcpf(e + 1.0f);
}

// LDS-only barrier: orders LDS traffic across waves without draining the
// vmem queue (keeps publish atomics fire-and-forget).
static __device__ __forceinline__ void barrier_lds() {
  asm volatile("s_waitcnt lgkmcnt(0)\n\ts_barrier" ::: "memory");
}

// Poll: 2 fast probes (atomic-or-0 at local XCD L2), then 1 agent mirror
// probe, repeat. Atomic-with-return bypasses L1 by construction.
static __device__ __forceinline__ unsigned long long poll_slot(
    unsigned long long* fast, const unsigned long long* mir, unsigned tag) {
  unsigned long long v;
  unsigned long long zero = 0;
  for (;;) {
#pragma unroll
    for (int k = 0; k < 2; ++k) {
      asm volatile("global_atomic_or_x2 %0, %1, %2, off sc0\n\t"
                   "s_waitcnt vmcnt(0)"
                   : "=&v"(v) : "v"(fast), "v"(zero) : "memory");
      if ((unsigned)(v >> 32) == tag) return v;
    }
    v = __hip_atomic_load(mir, __ATOMIC_RELAXED, __HIP_MEMORY_SCOPE_AGENT);
    if ((unsigned)(v >> 32) == tag) return v;
  }
}

// Publish: atomic swap at local XCD L2 (cannot be parked in L1) + agent mirror.
static __device__ __forceinline__ void publish_slot(
    unsigned long long* fast, unsigned long long* mir, unsigned long long pv) {
  asm volatile("global_atomic_swap_x2 %0, %1, off"
               :: "v"(fast), "v"(pv) : "memory");
  __hip_atomic_store(mir, pv, __ATOMIC_RELAXED, __HIP_MEMORY_SCOPE_AGENT);
}

// Deadlock-free single-XCD role election (el: [0..7]=cnt, [8]=winner(-1),
// [9]=role_cnt; zeroed by k_init each launch). Pigeonhole guarantees some
// XCD reaches NW registrants; first to do so wins; others exit.
static __device__ __forceinline__ int elect_role(int* el, int NW) {
  unsigned xcd;
  asm volatile("s_getreg_b32 %0, hwreg(HW_REG_XCC_ID)" : "=s"(xcd));
  xcd &= 7u;
  int r = __hip_atomic_fetch_add(&el[xcd], 1, __ATOMIC_RELAXED,
                                 __HIP_MEMORY_SCOPE_AGENT);
  if (r == NW - 1) {
    int exp = -1;
    __hip_atomic_compare_exchange_strong(&el[8], &exp, (int)xcd,
        __ATOMIC_RELAXED, __ATOMIC_RELAXED, __HIP_MEMORY_SCOPE_AGENT);
  }
  int w;
  while ((w = __hip_atomic_load(&el[8], __ATOMIC_RELAXED,
                                __HIP_MEMORY_SCOPE_AGENT)) < 0) {}
  if (w != (int)xcd) return -1;
  int rr = __hip_atomic_fetch_add(&el[9], 1, __ATOMIC_RELAXED,
                                  __HIP_MEMORY_SCOPE_AGENT);
  return (rr < NW) ? rr : -1;
}

__global__ void k_init(int* ec, int* ew) {
  int t = threadIdx.x;
  if (t < 10) ec[t] = (t == 8) ? -1 : 0;
  else if (t < 20) { int u = t - 10; ew[u] = (u == 8) ? -1 : 0; }
}

// ---------------------------------------------------------------------------
// K1a: char gate-input table: table[a][row] = b_r[row] + E_char[a,:]·W_ih_r[row,:]
// ---------------------------------------------------------------------------
__global__ void k_table(const float* __restrict__ Ec, const float* __restrict__ Wih,
                        const float* __restrict__ br, float* __restrict__ table) {
  __shared__ __align__(16) float e[ECH];
  int a = blockIdx.x, tid = threadIdx.x;
  if (tid < ECH) e[tid] = Ec[a * ECH + tid];
  __syncthreads();
  for (int row = tid; row < 4 * HR; row += 256) {
    const float4* w = (const float4*)(Wih + row * ECH);
    const float4* e4 = (const float4*)e;
    float acc = 0.f;
#pragma unroll
    for (int j = 0; j < ECH / 4; ++j) {
      float4 wv = w[j], ev = e4[j];
      acc += wv.x * ev.x + wv.y * ev.y + wv.z * ev.z + wv.w * ev.w;
    }
    table[a * (4 * HR) + row] = acc + br[row];
  }
}

// ---------------------------------------------------------------------------
// K1b: permute W_ih_w into k-major layout WT[k][p], p = (wg,gate,unit).
// ---------------------------------------------------------------------------
__global__ void k_permw(const float* __restrict__ Wihw, const float* __restrict__ bw,
                        float* __restrict__ WT, float* __restrict__ bperm) {
  int e = blockIdx.x * 256 + threadIdx.x;
  int p = e >> 8, k = e & 255;
  int r = p & 63, wgp = p >> 6;
  int R = (r >> 4) * HW + wgp * 16 + (r & 15);
  WT[k * (4 * HW) + p] = Wihw[R * (EW + DL) + k];
  if (k == 0) bperm[p] = bw[R];
}

// ---------------------------------------------------------------------------
// K2: persistent char LSTM. NWC WGs x 256 threads, elected onto one XCD.
// ---------------------------------------------------------------------------
__global__ __launch_bounds__(256) void k_char_lstm(
    const int* __restrict__ char_ids, const float* __restrict__ Whh,
    const float* __restrict__ table, unsigned long long* __restrict__ slots,
    unsigned long long* __restrict__ slotsM, int* __restrict__ elect,
    float* __restrict__ h_word)
{
  __shared__ int role_sh;
  if (threadIdx.x == 0) role_sh = elect_role(elect, NWC);
  __syncthreads();
  const int wg = role_sh;
  if (wg < 0) return;

  const int tid = threadIdx.x;
  const int wave = tid >> 6, lane = tid & 63;
  const int R = (lane >> 4) * HR + wg * 16 + (lane & 15);
  float4 wreg[16];
  {
    const float4* wp = (const float4*)(Whh + R * HR + wave * 64);
#pragma unroll
    for (int j = 0; j < 16; ++j) wreg[j] = wp[j];
  }
  __shared__ __align__(16) float tab[ALPHA * 64];
  __shared__ __align__(16) float hst[4][64];
  __shared__ float part[2][4][64];
  __shared__ float cst[16];
  for (int i = tid; i < ALPHA * 64; i += 256) {
    int chh = i >> 6, r = i & 63;
    int Rr = (r >> 4) * HR + wg * 16 + (r & 15);
    tab[i] = table[chh * (4 * HR) + Rr];
  }
  hst[wave][lane] = 0.f;
  if (tid < 16) cst[tid] = 0.f;
  __syncthreads();

#pragma unroll 1
  for (int t = 0; t < TCH; ++t) {
    int ch = char_ids[t];                    // uniform; overlaps the poll
    if (t > 0) {
      int par = (t - 1) & 1;
      unsigned long long v = poll_slot(slots + par * HR + tid,
                                       slotsM + par * HR + tid, (unsigned)t);
      hst[wave][lane] = __uint_as_float((unsigned)v);
      // same-wave LDS write->read; no barrier needed.
    }
    const float4* hp = (const float4*)hst[wave];
    float a0 = 0.f, a1 = 0.f, a2 = 0.f, a3 = 0.f;   // 4 chains: break FMA dep
#pragma unroll
    for (int j = 0; j < 4; ++j) {
      float4 h0 = hp[4*j+0], h1 = hp[4*j+1], h2 = hp[4*j+2], h3 = hp[4*j+3];
      float4 w0 = wreg[4*j+0], w1 = wreg[4*j+1], w2 = wreg[4*j+2], w3 = wreg[4*j+3];
      a0 += w0.x*h0.x + w0.y*h0.y + w0.z*h0.z + w0.w*h0.w;
      a1 += w1.x*h1.x + w1.y*h1.y + w1.z*h1.z + w1.w*h1.w;
      a2 += w2.x*h2.x + w2.y*h2.y + w2.z*h2.z + w2.w*h2.w;
      a3 += w3.x*h3.x + w3.y*h3.y + w3.z*h3.z + w3.w*h3.w;
    }
    float acc = (a0 + a1) + (a2 + a3);
    const int par = t & 1;
    part[par][wave][lane] = acc;
    barrier_lds();                            // LDS-only barrier per step
    if (wave == 0) {
      float z = ((part[par][0][lane] + part[par][1][lane]) +
                 (part[par][2][lane] + part[par][3][lane])) + tab[ch * 64 + lane];
      int u = lane & 15;                      // gate gather via shuffles
      float zi = __shfl(z, u,      64);
      float zf = __shfl(z, u + 16, 64);
      float zg = __shfl(z, u + 32, 64);
      float zo = __shfl(z, u + 48, 64);
      if (lane < 16) {
        float c = cst[lane];
        float ig = fsigmoid(zi), fg = fsigmoid(zf), og = fsigmoid(zo);
        float gg = ftanh(zg);
        c = fg * c + ig * gg;
        cst[lane] = c;
        float h = og * ftanh(c);
        unsigned long long pv =
            (((unsigned long long)(unsigned)(t + 1)) << 32) |
            (unsigned long long)__float_as_uint(h);
        int si = par * HR + wg * 16 + lane;
        publish_slot(slots + si, slotsM + si, pv);
        if ((t & 3) == 3) h_word[(t >> 2) * HR + wg * 16 + lane] = h;
      }
    }
    // no trailing barrier: part[] is parity-buffered (race-freedom in header).
  }
}

// ---------------------------------------------------------------------------
// K3a: latent = tanh(h_word @ W_lat^T + b_lat). One block per word.
// ---------------------------------------------------------------------------
__global__ __launch_bounds__(128) void k_latent(
    const float* __restrict__ hw, const float* __restrict__ Wlat,
    const float* __restrict__ blat, float* __restrict__ lat)
{
  int t = blockIdx.x, d = threadIdx.x;
  __shared__ __align__(16) float hh[HR];
  ((float2*)hh)[d] = ((const float2*)(hw + t * HR))[d];
  __syncthreads();
  const float4* w = (const float4*)(Wlat + d * HR);
  const float4* h4 = (const float4*)hh;
  float acc = 0.f;
#pragma unroll 8
  for (int j = 0; j < HR / 4; ++j) {
    float4 wv = w[j], hv = h4[j];
    acc += wv.x * hv.x + wv.y * hv.y + wv.z * hv.z + wv.w * hv.w;
  }
  lat[t * DL + d] = tanhf(acc + blat[d]);
}

// ---------------------------------------------------------------------------
// K3b: Xw[t][p] = bperm[p] + concat(E_word[wid[t]], latent[t]) · W row(p)
// ---------------------------------------------------------------------------
__global__ __launch_bounds__(256) void k_xw(
    const float* __restrict__ Ew, const int* __restrict__ wid,
    const float* __restrict__ lat, const float* __restrict__ WT,
    const float* __restrict__ bperm, float* __restrict__ Xw)
{
  int tblk = blockIdx.x, pblk = blockIdx.y;
  int tid = threadIdx.x;
  int p = pblk * 256 + tid;
  __shared__ __align__(16) float xt[32][256];
  int t0 = tblk * 32;
  for (int i = tid; i < 32 * 256; i += 256) {
    int tl = i >> 8, e = i & 255;
    int t = t0 + tl;
    float v;
    if (e < 128) v = Ew[wid[t] * EW + e];
    else         v = lat[t * DL + (e - 128)];
    xt[tl][e] = v;
  }
  __syncthreads();
  float acc[32];
#pragma unroll
  for (int i = 0; i < 32; ++i) acc[i] = 0.f;
  for (int k = 0; k < 256; k += 4) {
    float w0 = WT[(k + 0) * (4 * HW) + p];
    float w1 = WT[(k + 1) * (4 * HW) + p];
    float w2 = WT[(k + 2) * (4 * HW) + p];
    float w3 = WT[(k + 3) * (4 * HW) + p];
#pragma unroll
    for (int tl = 0; tl < 32; ++tl) {
      float4 x4 = *(const float4*)&xt[tl][k];
      acc[tl] += w0 * x4.x + w1 * x4.y + w2 * x4.z + w3 * x4.w;
    }
  }
  float b = bperm[p];
#pragma unroll
  for (int tl = 0; tl < 32; ++tl)
    Xw[(t0 + tl) * (4 * HW) + p] = acc[tl] + b;
}

// ---------------------------------------------------------------------------
// K4: persistent word LSTM. NWW WGs x 512 threads (8 waves), one XCD.
// ---------------------------------------------------------------------------
__global__ __launch_bounds__(512) void k_word_lstm(
    const float* __restrict__ Whh, const float* __restrict__ Xw,
    unsigned long long* __restrict__ slots, unsigned long long* __restrict__ slotsM,
    int* __restrict__ elect, float* __restrict__ out)
{
  __shared__ int role_sh;
  if (threadIdx.x == 0) role_sh = elect_role(elect, NWW);
  __syncthreads();
  const int wg = role_sh;
  if (wg < 0) return;

  const int tid = threadIdx.x;
  const int wave = tid >> 6, lane = tid & 63;
  const int R = (lane >> 4) * HW + wg * 16 + (lane & 15);
  float4 wreg[16];
  {
    const float4* wp = (const float4*)(Whh + R * HW + wave * 64);
#pragma unroll
    for (int j = 0; j < 16; ++j) wreg[j] = wp[j];
  }
  __shared__ __align__(16) float hst[8][64];
  __shared__ float part[2][8][64];
  __shared__ float cst[16];
  hst[wave][lane] = 0.f;
  if (tid < 16) cst[tid] = 0.f;
  __syncthreads();
  float xv = 0.f;
  if (wave == 0) xv = Xw[wg * 64 + lane];    // t=0 slice

#pragma unroll 1
  for (int t = 0; t < S_LEN; ++t) {
    float xn = 0.f;
    if (wave == 0) {                         // prefetch next x-slice
      int tt = (t + 1 < S_LEN) ? (t + 1) : t;
      xn = Xw[tt * (4 * HW) + wg * 64 + lane];
    }
    if (t > 0) {
      int par = (t - 1) & 1;
      unsigned long long v = poll_slot(slots + par * HW + tid,
                                       slotsM + par * HW + tid, (unsigned)t);
      hst[wave][lane] = __uint_as_float((unsigned)v);
    }
    const float4* hp = (const float4*)hst[wave];
    float a0 = 0.f, a1 = 0.f, a2 = 0.f, a3 = 0.f;
#pragma unroll
    for (int j = 0; j < 4; ++j) {
      float4 h0 = hp[4*j+0], h1 = hp[4*j+1], h2 = hp[4*j+2], h3 = hp[4*j+3];
      float4 w0 = wreg[4*j+0], w1 = wreg[4*j+1], w2 = wreg[4*j+2], w3 = wreg[4*j+3];
      a0 += w0.x*h0.x + w0.y*h0.y + w0.z*h0.z + w0.w*h0.w;
      a1 += w1.x*h1.x + w1.y*h1.y + w1.z*h1.z + w1.w*h1.w;
      a2 += w2.x*h2.x + w2.y*h2.y + w2.z*h2.z + w2.w*h2.w;
      a3 += w3.x*h3.x + w3.y*h3.y + w3.z*h3.z + w3.w*h3.w;
    }
    float acc = (a0 + a1) + (a2 + a3);
    const int par = t & 1;
    part[par][wave][lane] = acc;
    barrier_lds();
    if (wave == 0) {
      float z = (((part[par][0][lane] + part[par][1][lane]) +
                  (part[par][2][lane] + part[par][3][lane])) +
                 ((part[par][4][lane] + part[par][5][lane]) +
                  (part[par][6][lane] + part[par][7][lane]))) + xv;
      int u = lane & 15;
      float zi = __shfl(z, u,      64);
      float zf = __shfl(z, u + 16, 64);
      float zg = __shfl(z, u + 32, 64);
      float zo = __shfl(z, u + 48, 64);
      if (lane < 16) {
        float c = cst[lane];
        float ig = fsigmoid(zi), fg = fsigmoid(zf), og = fsigmoid(zo);
        float gg = ftanh(zg);
        c = fg * c + ig * gg;
        cst[lane] = c;
        float h = og * ftanh(c);
        unsigned long long pv =
            (((unsigned long long)(unsigned)(t + 1)) << 32) |
            (unsigned long long)__float_as_uint(h);
        int si = par * HW + wg * 16 + lane;
        publish_slot(slots + si, slotsM + si, pv);
        out[t * HW + wg * 16 + lane] = h;
      }
    }
    xv = xn;
  }
}

// ---------------------------------------------------------------------------
extern "C" void kernel_launch(void* const* d_in, const int* in_sizes, int n_in,
                              void* d_out, int out_size, void* d_ws, size_t ws_size,
                              hipStream_t stream) {
  const float* E_char = (const float*)d_in[0];
  const float* W_ih_r = (const float*)d_in[1];
  const float* W_hh_r = (const float*)d_in[2];
  const float* b_r    = (const float*)d_in[3];
  const float* W_lat  = (const float*)d_in[4];
  const float* b_lat  = (const float*)d_in[5];
  const float* E_word = (const float*)d_in[6];
  const float* W_ih_w = (const float*)d_in[7];
  const float* W_hh_w = (const float*)d_in[8];
  const float* b_w    = (const float*)d_in[9];
  const int* word_ids = (const int*)d_in[10];
  const int* char_ids = (const int*)d_in[11];

  char* ws = (char*)d_ws;
  float*              tableR  = (float*)(ws + 0x000000);             // 100 KB
  unsigned long long* slotsC  = (unsigned long long*)(ws + 0x20000); // 4 KB
  unsigned long long* slotsCM = (unsigned long long*)(ws + 0x22000); // 4 KB
  unsigned long long* slotsW  = (unsigned long long*)(ws + 0x24000); // 8 KB
  unsigned long long* slotsWM = (unsigned long long*)(ws + 0x26000); // 8 KB
  int*                electC  = (int*)(ws + 0x28000);
  int*                electW  = (int*)(ws + 0x28100);
  float*              h_word  = (float*)(ws + 0x030000);             // 4 MB
  float*              latent  = (float*)(ws + 0x430000);             // 2 MB
  float*              WT      = (float*)(ws + 0x630000);             // 2 MB
  float*              bperm   = (float*)(ws + 0x830000);             // 8 KB
  float*              Xw      = (float*)(ws + 0x840000);             // 32 MB
  float* out = (float*)d_out;

  hipLaunchKernelGGL(k_init,      dim3(1),       dim3(64),  0, stream,
                     electC, electW);
  hipLaunchKernelGGL(k_table,     dim3(ALPHA),   dim3(256), 0, stream,
                     E_char, W_ih_r, b_r, tableR);
  hipLaunchKernelGGL(k_permw,     dim3(2048),    dim3(256), 0, stream,
                     W_ih_w, b_w, WT, bperm);
  hipLaunchKernelGGL(k_char_lstm, dim3(GRIDC),   dim3(256), 0, stream,
                     char_ids, W_hh_r, tableR, slotsC, slotsCM, electC, h_word);
  hipLaunchKernelGGL(k_latent,    dim3(S_LEN),   dim3(128), 0, stream,
                     h_word, W_lat, b_lat, latent);
  hipLaunchKernelGGL(k_xw,        dim3(128, 8),  dim3(256), 0, stream,
                     E_word, word_ids, latent, WT, bperm, Xw);
  hipLaunchKernelGGL(k_word_lstm, dim3(GRIDW),   dim3(512), 0, stream,
                     W_hh_w, Xw, slotsW, slotsWM, electW, out);
}